// Round 16
// baseline (145.030 us; speedup 1.0000x reference)
//
#include <hip/hip_runtime.h>
#include <math.h>

// GenSP: SSN superpixels, x(1,64,384,384), stoken=16.
// S=576 superpixels (24x24 grid of 16x16 px blocks), C=64, P=147456, N_ITER=3.
// f64 label chain (R1/R3/R4/R6/R12/R13/R15 bit-matched np f64 ref, absmax 0.0).
// R16 = R15 + paired-chunk heavy blocks: 128 thr / 2 waves, each wave runs one
// 32px chunk with the R13 body verbatim; shared scent staging + LDS pairwise
// partial combine -> bnum halves to 10.6MB, gathers read half. Wave count
// unchanged (4608); no cross-wave deps in compute phases (R8's failure mode).

#define NC   64
#define IMW  384
#define HWP  (384*384)
#define NSH  24
#define NSW  24
#define NS   (NSH*NSW)
#define NPB  (NS*4)       // 2304 pair-blocks (4 pairs x 2 chunks of 32px per b)

// ---- K1: fused initial centroids + cnorm (576 blocks x 256 thr) -----------
__global__ __launch_bounds__(256) void k_cent_init(const float* __restrict__ x,
                                                   double* __restrict__ cent,
                                                   double* __restrict__ cnorm) {
    int s = blockIdx.x, by = s / NSW, bx = s % NSW;
    int t = threadIdx.x, q = t >> 2, r = t & 3;
    __shared__ double wl[4];
    const float* gp = x + (size_t)q * HWP + (size_t)(by * 16) * IMW + bx * 16 + r * 4;
    double sg[4];
    #pragma unroll
    for (int g = 0; g < 4; ++g) {        // per-g partial, R4's exact order
        double s2 = 0.0;
        #pragma unroll
        for (int j = 0; j < 4; ++j) {
            float4 v = *(const float4*)(gp + (size_t)(g * 4 + j) * IMW);
            s2 += (double)v.x; s2 += (double)v.y; s2 += (double)v.z; s2 += (double)v.w;
        }
        s2 += __shfl_xor(s2, 1, 64);
        s2 += __shfl_xor(s2, 2, 64);
        sg[g] = s2;
    }
    double v = (((sg[0] + sg[1]) + sg[2]) + sg[3]) * (1.0 / 256.0);
    if (r == 0) cent[s * NC + q] = v;
    double n2 = (r == 0) ? v * v : 0.0;
    #pragma unroll
    for (int off = 32; off >= 1; off >>= 1) n2 += __shfl_xor(n2, off, 64);
    if ((t & 63) == 0) wl[t >> 6] = n2;
    __syncthreads();
    if (t == 0) cnorm[s] = ((wl[0] + wl[1]) + wl[2]) + wl[3];
}

// ---- K2: soft iteration: pair-block, wave w owns chunk g = pr*2 + w -------
__global__ __launch_bounds__(128) void k_iter(const float* __restrict__ x,
        const double* __restrict__ cent, const double* __restrict__ cnorm,
        double* __restrict__ bnum, double* __restrict__ bden) {
    int bg2 = blockIdx.x, b = bg2 >> 2, pr = bg2 & 3;
    int by = b / NSW, bx = b % NSW;
    int t = threadIdx.x, w = t >> 6, tl = t & 63;
    int p = tl & 31, h = tl >> 5;        // pixel in chunk, channel-half
    int g = pr * 2 + w;                  // this wave's chunk
    __shared__ double scent[9][64];      // 4.6 KB; reused as pnum after dot
    __shared__ double aff[2][9][33];     // 4.75 KB, per-wave
    __shared__ double lden[2][9];
    double* pnum = &scent[0][0];

    int cand[9]; bool vld[9];
    #pragma unroll
    for (int k = 0; k < 9; ++k) {        // pure blockIdx math -> SGPR
        int cy = by + k / 3 - 1, cx = bx + k % 3 - 1;
        vld[k] = (cy >= 0) && (cy < NSH) && (cx >= 0) && (cx < NSW);
        cand[k] = vld[k] ? (cy * NSW + cx) : 0;
    }

    // cooperative scent staging (one per pair-block, halves cent traffic)
    for (int idx = t; idx < 9 * NC; idx += 128)
        scent[idx >> 6][idx & 63] = cent[(size_t)cand[idx >> 6] * NC + (idx & 63)];
    __syncthreads();

    // distance: R13 body (32 channels/thread, halves combined in-wave)
    const float* xp = x + (size_t)(by * 16 + g * 2 + (p >> 4)) * IMW + bx * 16 + (p & 15);
    double dot[9] = {0, 0, 0, 0, 0, 0, 0, 0, 0};
    #pragma unroll 4
    for (int i = 0; i < 32; ++i) {
        int c = h * 32 + i;
        double xv = (double)xp[(size_t)c * HWP];
        #pragma unroll
        for (int k = 0; k < 9; ++k)
            dot[k] = fma(xv, scent[k][c], dot[k]);
    }
    #pragma unroll
    for (int k = 0; k < 9; ++k) dot[k] += __shfl_xor(dot[k], 32, 64);

    double d[9], m = -1e300;
    #pragma unroll
    for (int k = 0; k < 9; ++k) {
        d[k] = fma(dot[k], -2.0, cnorm[cand[k]]);
        if (vld[k]) m = fmax(m, -d[k]);
    }
    double e[9], ss = 0.0;
    #pragma unroll
    for (int k = 0; k < 9; ++k) { e[k] = vld[k] ? exp(-d[k] - m) : 0.0; ss += e[k]; }
    double inv = 1.0 / ss;
    #pragma unroll
    for (int k = 0; k < 9; ++k) {
        e[k] *= inv;
        if (h == 0) aff[w][k][p] = e[k];
    }
    #pragma unroll
    for (int k = 0; k < 9; ++k) {        // den over the 32 px (R13 order)
        double dn = e[k];
        #pragma unroll
        for (int off = 16; off >= 1; off >>= 1) dn += __shfl_down(dn, off, 64);
        if (tl == 0) lden[w][k] = dn;
    }
    __syncthreads();                     // aff/lden ready; scent consumed

    // dot phase: R13 body against this wave's aff
    int c = tl;
    double acc[9] = {0, 0, 0, 0, 0, 0, 0, 0, 0};
    const float* xq = x + (size_t)c * HWP + (size_t)(by * 16 + g * 2) * IMW + bx * 16;
    #pragma unroll
    for (int r = 0; r < 2; ++r) {
        #pragma unroll
        for (int q = 0; q < 4; ++q) {
            float4 xw = *(const float4*)(xq + (size_t)r * IMW + q * 4);
            int pp = r * 16 + q * 4;
            #pragma unroll
            for (int k = 0; k < 9; ++k) {
                acc[k] = fma(aff[w][k][pp + 0], (double)xw.x, acc[k]);
                acc[k] = fma(aff[w][k][pp + 1], (double)xw.y, acc[k]);
                acc[k] = fma(aff[w][k][pp + 2], (double)xw.z, acc[k]);
                acc[k] = fma(aff[w][k][pp + 3], (double)xw.w, acc[k]);
            }
        }
    }
    // pairwise combine (even + odd) -> single store per pair-block
    if (w == 1) {
        #pragma unroll
        for (int k = 0; k < 9; ++k) pnum[k * 64 + c] = acc[k];
    }
    __syncthreads();
    if (w == 0) {
        #pragma unroll
        for (int k = 0; k < 9; ++k)
            bnum[((size_t)bg2 * 9 + k) * NC + c] = acc[k] + pnum[k * 64 + c];
        if (tl == 0) {
            #pragma unroll
            for (int k = 0; k < 9; ++k)
                bden[(size_t)bg2 * 9 + k] = lden[0][k] + lden[1][k];
        }
    }
}

// ---- K3: centroid update: 4-wave gather (wave j owns pair j) --------------
__global__ __launch_bounds__(256) void k_gather_cent(const double* __restrict__ bnum,
                                                     const double* __restrict__ bden,
                                                     double* __restrict__ cent,
                                                     double* __restrict__ cnorm) {
    int s = blockIdx.x, t = threadIdx.x, c = t & 63, j = t >> 6;
    int sy = s / NSW, sx = s % NSW;
    __shared__ double lnum[4][64];
    __shared__ double lden[4];
    double num = 0.0, den = 0.0;
    #pragma unroll
    for (int k = 0; k < 9; ++k) {
        int by2 = sy - (k / 3 - 1), bx2 = sx - (k % 3 - 1);
        if (by2 >= 0 && by2 < NSH && bx2 >= 0 && bx2 < NSW) {
            int bg2 = (by2 * NSW + bx2) * 4 + j;
            num += bnum[((size_t)bg2 * 9 + k) * NC + c];
            den += bden[(size_t)bg2 * 9 + k];
        }
    }
    lnum[j][c] = num;
    if (c == 0) lden[j] = den;
    __syncthreads();
    if (t < 64) {
        double nt = ((lnum[0][c] + lnum[1][c]) + lnum[2][c]) + lnum[3][c];
        double dt = ((lden[0] + lden[1]) + lden[2]) + lden[3];
        double v = nt / (dt + 1e-16);
        cent[s * NC + c] = v;
        double n2 = v * v;
        #pragma unroll
        for (int off = 32; off >= 1; off >>= 1) n2 += __shfl_down(n2, off, 64);
        if (c == 0) cnorm[s] = n2;
    }
}

// ---- K4: final: pair-block argmin labels + hard-label partials ------------
__global__ __launch_bounds__(128) void k_final(const float* __restrict__ x,
        const double* __restrict__ cent, const double* __restrict__ cnorm,
        int* __restrict__ labels,
        double* __restrict__ bnum, double* __restrict__ bden) {
    int bg2 = blockIdx.x, b = bg2 >> 2, pr = bg2 & 3;
    int by = b / NSW, bx = b % NSW;
    int t = threadIdx.x, w = t >> 6, tl = t & 63;
    int p = tl & 31, h = tl >> 5;
    int g = pr * 2 + w;
    __shared__ double scent[9][64];
    __shared__ double aff[2][9][33];
    __shared__ double lden[2][9];
    double* pnum = &scent[0][0];

    int cand[9]; bool vld[9];
    #pragma unroll
    for (int k = 0; k < 9; ++k) {
        int cy = by + k / 3 - 1, cx = bx + k % 3 - 1;
        vld[k] = (cy >= 0) && (cy < NSH) && (cx >= 0) && (cx < NSW);
        cand[k] = vld[k] ? (cy * NSW + cx) : 0;
    }
    for (int idx = t; idx < 9 * NC; idx += 128)
        scent[idx >> 6][idx & 63] = cent[(size_t)cand[idx >> 6] * NC + (idx & 63)];
    __syncthreads();

    const float* xp = x + (size_t)(by * 16 + g * 2 + (p >> 4)) * IMW + bx * 16 + (p & 15);
    double dot[9] = {0, 0, 0, 0, 0, 0, 0, 0, 0};
    #pragma unroll 4
    for (int i = 0; i < 32; ++i) {
        int c = h * 32 + i;
        double xv = (double)xp[(size_t)c * HWP];
        #pragma unroll
        for (int k = 0; k < 9; ++k)
            dot[k] = fma(xv, scent[k][c], dot[k]);
    }
    #pragma unroll
    for (int k = 0; k < 9; ++k) dot[k] += __shfl_xor(dot[k], 32, 64);

    double bestd = 1e300; int bk = 0;
    #pragma unroll
    for (int k = 0; k < 9; ++k) {
        double dv = fma(dot[k], -2.0, cnorm[cand[k]]);
        if (vld[k] && dv < bestd) { bestd = dv; bk = k; }   // first-wins
    }
    if (h == 0) {
        labels[(size_t)(by * 16 + g * 2 + (p >> 4)) * IMW + bx * 16 + (p & 15)] =
            (by + bk / 3 - 1) * NSW + (bx + bk % 3 - 1);
        #pragma unroll
        for (int k = 0; k < 9; ++k) aff[w][k][p] = (bk == k) ? 1.0 : 0.0;
    }
    #pragma unroll
    for (int k = 0; k < 9; ++k) {        // counts over the 32 px
        int cnt = (bk == k);
        #pragma unroll
        for (int off = 16; off >= 1; off >>= 1) cnt += __shfl_down(cnt, off, 64);
        if (tl == 0) lden[w][k] = (double)cnt;
    }
    __syncthreads();

    int c = tl;
    double acc[9] = {0, 0, 0, 0, 0, 0, 0, 0, 0};
    const float* xq = x + (size_t)c * HWP + (size_t)(by * 16 + g * 2) * IMW + bx * 16;
    #pragma unroll
    for (int r = 0; r < 2; ++r) {
        #pragma unroll
        for (int q = 0; q < 4; ++q) {
            float4 xw = *(const float4*)(xq + (size_t)r * IMW + q * 4);
            int pp = r * 16 + q * 4;
            #pragma unroll
            for (int k = 0; k < 9; ++k) {
                acc[k] = fma(aff[w][k][pp + 0], (double)xw.x, acc[k]);
                acc[k] = fma(aff[w][k][pp + 1], (double)xw.y, acc[k]);
                acc[k] = fma(aff[w][k][pp + 2], (double)xw.z, acc[k]);
                acc[k] = fma(aff[w][k][pp + 3], (double)xw.w, acc[k]);
            }
        }
    }
    if (w == 1) {
        #pragma unroll
        for (int k = 0; k < 9; ++k) pnum[k * 64 + c] = acc[k];
    }
    __syncthreads();
    if (w == 0) {
        #pragma unroll
        for (int k = 0; k < 9; ++k)
            bnum[((size_t)bg2 * 9 + k) * NC + c] = acc[k] + pnum[k * 64 + c];
        if (tl == 0) {
            #pragma unroll
            for (int k = 0; k < 9; ++k)
                bden[(size_t)bg2 * 9 + k] = lden[0][k] + lden[1][k];
        }
    }
}

// ---- K5: paint means: 4-wave gather (wave j owns pair j) ------------------
__global__ __launch_bounds__(256) void k_means_(const double* __restrict__ bnum,
                                                const double* __restrict__ bden,
                                                float* __restrict__ means) {
    int s = blockIdx.x, t = threadIdx.x, c = t & 63, j = t >> 6;
    int sy = s / NSW, sx = s % NSW;
    __shared__ double lnum[4][64];
    __shared__ double lden[4];
    double num = 0.0, den = 0.0;
    #pragma unroll
    for (int k = 0; k < 9; ++k) {
        int by2 = sy - (k / 3 - 1), bx2 = sx - (k % 3 - 1);
        if (by2 >= 0 && by2 < NSH && bx2 >= 0 && bx2 < NSW) {
            int bg2 = (by2 * NSW + bx2) * 4 + j;
            num += bnum[((size_t)bg2 * 9 + k) * NC + c];
            den += bden[(size_t)bg2 * 9 + k];
        }
    }
    lnum[j][c] = num;
    if (c == 0) lden[j] = den;
    __syncthreads();
    if (t < 64) {
        double nt = ((lnum[0][c] + lnum[1][c]) + lnum[2][c]) + lnum[3][c];
        double dt = ((lden[0] + lden[1]) + lden[2]) + lden[3];
        means[s * NC + c] = (float)(nt / fmax(dt, 1.0));
    }
}

// ---- K6: paint out[c][p] = means[lab[p]][c]; 4 px x 4 ch per thread -------
__global__ __launch_bounds__(256) void k_paint(const int* __restrict__ labels,
                                               const float* __restrict__ means,
                                               float* __restrict__ out) {
    int p0 = (blockIdx.x * 256 + threadIdx.x) * 4;
    int4 lb = *(const int4*)&labels[p0];
    int c0 = blockIdx.y * 4;
    #pragma unroll
    for (int j = 0; j < 4; ++j) {
        int c = c0 + j;
        float4 o;
        o.x = means[lb.x * NC + c];
        o.y = means[lb.y * NC + c];
        o.z = means[lb.z * NC + c];
        o.w = means[lb.w * NC + c];
        *(float4*)&out[(size_t)c * HWP + p0] = o;
    }
}

extern "C" void kernel_launch(void* const* d_in, const int* in_sizes, int n_in,
                              void* d_out, int out_size, void* d_ws, size_t ws_size,
                              hipStream_t stream) {
    const float* x = (const float*)d_in[0];
    float* out = (float*)d_out;
    char* ws = (char*)d_ws;
    char* od = (char*)d_out;

    constexpr size_t CENT_B  = (size_t)NS * NC * 8;       // 294912 (x2)
    constexpr size_t CNRM_B  = (size_t)NS * 8;            // 4608   (x2)
    constexpr size_t BNUM_B  = (size_t)NPB * 9 * NC * 8;  // 10616832
    constexpr size_t BDEN_B  = (size_t)NPB * 9 * 8;       // 165888
    constexpr size_t LAB_B   = (size_t)HWP * 4;           // 589824
    constexpr size_t MEANS_B = (size_t)NS * NC * 4;       // 147456
    constexpr size_t T_PAINT = LAB_B + MEANS_B;           // must live in ws
    constexpr size_t T_CENT  = T_PAINT + 2 * (CENT_B + CNRM_B);
    constexpr size_t T_ALL   = T_CENT + BNUM_B + BDEN_B;  // ~12.3 MB

    int* labels = (int*)ws;
    float* means = (float*)(ws + LAB_B);
    double *centA, *centB, *cnormA, *cnormB, *bnum, *bden;
    if (ws_size >= T_ALL) {
        centA  = (double*)(ws + T_PAINT);
        centB  = (double*)(ws + T_PAINT + CENT_B);
        cnormA = (double*)(ws + T_PAINT + 2 * CENT_B);
        cnormB = (double*)(ws + T_PAINT + 2 * CENT_B + CNRM_B);
        bnum   = (double*)(ws + T_CENT);
        bden   = (double*)(ws + T_CENT + BNUM_B);
    } else if (ws_size >= T_CENT) {
        centA  = (double*)(ws + T_PAINT);
        centB  = (double*)(ws + T_PAINT + CENT_B);
        cnormA = (double*)(ws + T_PAINT + 2 * CENT_B);
        cnormB = (double*)(ws + T_PAINT + 2 * CENT_B + CNRM_B);
        bnum   = (double*)od;
        bden   = (double*)(od + BNUM_B);
    } else {
        bnum   = (double*)od;
        bden   = (double*)(od + BNUM_B);
        centA  = (double*)(od + BNUM_B + BDEN_B);
        centB  = (double*)(od + BNUM_B + BDEN_B + CENT_B);
        cnormA = (double*)(od + BNUM_B + BDEN_B + 2 * CENT_B);
        cnormB = (double*)(od + BNUM_B + BDEN_B + 2 * CENT_B + CNRM_B);
    }
    // all d_out-resident scratch (<11.5 MB) is consumed before k_paint
    // fully overwrites d_out (37.7 MB)

    k_cent_init<<<NS, 256, 0, stream>>>(x, centA, cnormA);
    k_iter<<<NPB, 128, 0, stream>>>(x, centA, cnormA, bnum, bden);
    k_gather_cent<<<NS, 256, 0, stream>>>(bnum, bden, centB, cnormB);
    k_iter<<<NPB, 128, 0, stream>>>(x, centB, cnormB, bnum, bden);
    k_gather_cent<<<NS, 256, 0, stream>>>(bnum, bden, centA, cnormA);
    k_final<<<NPB, 128, 0, stream>>>(x, centA, cnormA, labels, bnum, bden);
    k_means_<<<NS, 256, 0, stream>>>(bnum, bden, means);
    k_paint<<<dim3(HWP / 1024, NC / 4), 256, 0, stream>>>(labels, means, out);
}

// Round 18
// 116.569 us; speedup vs baseline: 1.2442x; 1.2442x over previous
//
#include <hip/hip_runtime.h>
#include <math.h>

// GenSP: SSN superpixels, x(1,64,384,384), stoken=16.
// S=576 superpixels (24x24 grid of 16x16 px blocks), C=64, P=147456, N_ITER=3.
// f64 label chain (R1/R3/R4/R6/R12/R13/R15 bit-matched np f64 ref, absmax 0.0).
// R17 = R15 VERBATIM (session best, 117.2us). R16's 2-wave pairing regressed
// (145us): pairing barriers + store-tail serialization > partials-BW savings.
// Third data point that 64-thread fully-independent heavy blocks win here.

#define NC   64
#define IMW  384
#define HWP  (384*384)
#define NSH  24
#define NSW  24
#define NS   (NSH*NSW)
#define NBG  (NS*8)       // 4608 iter chunks (8 x 32px per superpixel block)

// ---- K1: fused initial centroids + cnorm (576 blocks x 256 thr) -----------
__global__ __launch_bounds__(256) void k_cent_init(const float* __restrict__ x,
                                                   double* __restrict__ cent,
                                                   double* __restrict__ cnorm) {
    int s = blockIdx.x, by = s / NSW, bx = s % NSW;
    int t = threadIdx.x, q = t >> 2, r = t & 3;
    __shared__ double wl[4];
    const float* gp = x + (size_t)q * HWP + (size_t)(by * 16) * IMW + bx * 16 + r * 4;
    double sg[4];
    #pragma unroll
    for (int g = 0; g < 4; ++g) {        // per-g partial, R4's exact order
        double s2 = 0.0;
        #pragma unroll
        for (int j = 0; j < 4; ++j) {
            float4 v = *(const float4*)(gp + (size_t)(g * 4 + j) * IMW);
            s2 += (double)v.x; s2 += (double)v.y; s2 += (double)v.z; s2 += (double)v.w;
        }
        s2 += __shfl_xor(s2, 1, 64);
        s2 += __shfl_xor(s2, 2, 64);
        sg[g] = s2;
    }
    double v = (((sg[0] + sg[1]) + sg[2]) + sg[3]) * (1.0 / 256.0);
    if (r == 0) cent[s * NC + q] = v;
    double n2 = (r == 0) ? v * v : 0.0;
    #pragma unroll
    for (int off = 32; off >= 1; off >>= 1) n2 += __shfl_xor(n2, off, 64);
    if ((t & 63) == 0) wl[t >> 6] = n2;
    __syncthreads();
    if (t == 0) cnorm[s] = ((wl[0] + wl[1]) + wl[2]) + wl[3];
}

// ---- K2: soft iteration: 32px chunk, 2 threads/px (R13 verbatim) ----------
__global__ __launch_bounds__(64) void k_iter(const float* __restrict__ x,
        const double* __restrict__ cent, const double* __restrict__ cnorm,
        double* __restrict__ bnum, double* __restrict__ bden) {
    int bg = blockIdx.x, b = bg >> 3, g = bg & 7;
    int by = b / NSW, bx = b % NSW;
    int t = threadIdx.x;
    int p = t & 31, h = t >> 5;          // pixel in chunk, channel-half
    __shared__ double scent[9][64];      // 4.6 KB staged candidate centroids
    __shared__ double aff[9][33];        // 2.3 KB

    int cand[9]; bool vld[9];
    #pragma unroll
    for (int k = 0; k < 9; ++k) {        // pure blockIdx math -> SGPR
        int cy = by + k / 3 - 1, cx = bx + k % 3 - 1;
        vld[k] = (cy >= 0) && (cy < NSH) && (cx >= 0) && (cx < NSW);
        cand[k] = vld[k] ? (cy * NSW + cx) : 0;
    }

    // stage: 9 coalesced 512B row loads (R12, validated)
    #pragma unroll
    for (int j = 0; j < 9; ++j)
        scent[j][t] = cent[(size_t)cand[j] * NC + t];
    __syncthreads();

    // distance: 32 channels per thread, halves combined in-wave
    const float* xp = x + (size_t)(by * 16 + g * 2 + (p >> 4)) * IMW + bx * 16 + (p & 15);
    double dot[9] = {0, 0, 0, 0, 0, 0, 0, 0, 0};
    #pragma unroll 4
    for (int i = 0; i < 32; ++i) {
        int c = h * 32 + i;
        double xv = (double)xp[(size_t)c * HWP];
        #pragma unroll
        for (int k = 0; k < 9; ++k)
            dot[k] = fma(xv, scent[k][c], dot[k]);
    }
    #pragma unroll
    for (int k = 0; k < 9; ++k) dot[k] += __shfl_xor(dot[k], 32, 64);

    double d[9], m = -1e300;
    #pragma unroll
    for (int k = 0; k < 9; ++k) {
        d[k] = fma(dot[k], -2.0, cnorm[cand[k]]);
        if (vld[k]) m = fmax(m, -d[k]);
    }
    double e[9], ss = 0.0;
    #pragma unroll
    for (int k = 0; k < 9; ++k) { e[k] = vld[k] ? exp(-d[k] - m) : 0.0; ss += e[k]; }
    double inv = 1.0 / ss;
    #pragma unroll
    for (int k = 0; k < 9; ++k) {
        e[k] *= inv;
        if (h == 0) aff[k][p] = e[k];
    }

    #pragma unroll
    for (int k = 0; k < 9; ++k) {        // den over the 32 px (lanes 0..31)
        double dn = e[k];
        #pragma unroll
        for (int off = 16; off >= 1; off >>= 1) dn += __shfl_down(dn, off, 64);
        if (t == 0) bden[(size_t)bg * 9 + k] = dn;
    }
    __syncthreads();

    // dot phase: lane = channel; 2 rows x 4 float4 (L2-hot), aff broadcast
    int c = t;
    double acc[9] = {0, 0, 0, 0, 0, 0, 0, 0, 0};
    const float* xq = x + (size_t)c * HWP + (size_t)(by * 16 + g * 2) * IMW + bx * 16;
    #pragma unroll
    for (int r = 0; r < 2; ++r) {
        #pragma unroll
        for (int q = 0; q < 4; ++q) {
            float4 xw = *(const float4*)(xq + (size_t)r * IMW + q * 4);
            int pp = r * 16 + q * 4;
            #pragma unroll
            for (int k = 0; k < 9; ++k) {
                acc[k] = fma(aff[k][pp + 0], (double)xw.x, acc[k]);
                acc[k] = fma(aff[k][pp + 1], (double)xw.y, acc[k]);
                acc[k] = fma(aff[k][pp + 2], (double)xw.z, acc[k]);
                acc[k] = fma(aff[k][pp + 3], (double)xw.w, acc[k]);
            }
        }
    }
    #pragma unroll
    for (int k = 0; k < 9; ++k) bnum[((size_t)bg * 9 + k) * NC + c] = acc[k];
}

// ---- K3: centroid update: 4-wave gather (wave j owns g = 2j, 2j+1) --------
__global__ __launch_bounds__(256) void k_gather_cent(const double* __restrict__ bnum,
                                                     const double* __restrict__ bden,
                                                     double* __restrict__ cent,
                                                     double* __restrict__ cnorm) {
    int s = blockIdx.x, t = threadIdx.x, c = t & 63, j = t >> 6;
    int sy = s / NSW, sx = s % NSW;
    __shared__ double lnum[4][64];
    __shared__ double lden[4];
    double num = 0.0, den = 0.0;
    #pragma unroll
    for (int k = 0; k < 9; ++k) {
        int by2 = sy - (k / 3 - 1), bx2 = sx - (k % 3 - 1);
        if (by2 >= 0 && by2 < NSH && bx2 >= 0 && bx2 < NSW) {
            int b2 = by2 * NSW + bx2;
            #pragma unroll
            for (int gg = 0; gg < 2; ++gg) {
                int bg = b2 * 8 + j * 2 + gg;
                num += bnum[((size_t)bg * 9 + k) * NC + c];
                den += bden[(size_t)bg * 9 + k];
            }
        }
    }
    lnum[j][c] = num;
    if (c == 0) lden[j] = den;
    __syncthreads();
    if (t < 64) {
        double nt = ((lnum[0][c] + lnum[1][c]) + lnum[2][c]) + lnum[3][c];
        double dt = ((lden[0] + lden[1]) + lden[2]) + lden[3];
        double v = nt / (dt + 1e-16);
        cent[s * NC + c] = v;
        double n2 = v * v;
        #pragma unroll
        for (int off = 32; off >= 1; off >>= 1) n2 += __shfl_down(n2, off, 64);
        if (c == 0) cnorm[s] = n2;
    }
}

// ---- K4: final: argmin labels + hard-label partials (R13 verbatim) --------
__global__ __launch_bounds__(64) void k_final(const float* __restrict__ x,
        const double* __restrict__ cent, const double* __restrict__ cnorm,
        int* __restrict__ labels,
        double* __restrict__ bnum, double* __restrict__ bden) {
    int bg = blockIdx.x, b = bg >> 3, g = bg & 7;
    int by = b / NSW, bx = b % NSW;
    int t = threadIdx.x;
    int p = t & 31, h = t >> 5;
    __shared__ double scent[9][64];
    __shared__ double aff[9][33];

    int cand[9]; bool vld[9];
    #pragma unroll
    for (int k = 0; k < 9; ++k) {
        int cy = by + k / 3 - 1, cx = bx + k % 3 - 1;
        vld[k] = (cy >= 0) && (cy < NSH) && (cx >= 0) && (cx < NSW);
        cand[k] = vld[k] ? (cy * NSW + cx) : 0;
    }

    #pragma unroll
    for (int j = 0; j < 9; ++j)
        scent[j][t] = cent[(size_t)cand[j] * NC + t];
    __syncthreads();

    const float* xp = x + (size_t)(by * 16 + g * 2 + (p >> 4)) * IMW + bx * 16 + (p & 15);
    double dot[9] = {0, 0, 0, 0, 0, 0, 0, 0, 0};
    #pragma unroll 4
    for (int i = 0; i < 32; ++i) {
        int c = h * 32 + i;
        double xv = (double)xp[(size_t)c * HWP];
        #pragma unroll
        for (int k = 0; k < 9; ++k)
            dot[k] = fma(xv, scent[k][c], dot[k]);
    }
    #pragma unroll
    for (int k = 0; k < 9; ++k) dot[k] += __shfl_xor(dot[k], 32, 64);

    double bestd = 1e300; int bk = 0;
    #pragma unroll
    for (int k = 0; k < 9; ++k) {
        double dv = fma(dot[k], -2.0, cnorm[cand[k]]);
        if (vld[k] && dv < bestd) { bestd = dv; bk = k; }   // first-wins
    }
    if (h == 0) {
        labels[(size_t)(by * 16 + g * 2 + (p >> 4)) * IMW + bx * 16 + (p & 15)] =
            (by + bk / 3 - 1) * NSW + (bx + bk % 3 - 1);
        #pragma unroll
        for (int k = 0; k < 9; ++k) aff[k][p] = (bk == k) ? 1.0 : 0.0;
    }

    #pragma unroll
    for (int k = 0; k < 9; ++k) {        // counts over the 32 px
        int cnt = (bk == k);
        #pragma unroll
        for (int off = 16; off >= 1; off >>= 1) cnt += __shfl_down(cnt, off, 64);
        if (t == 0) bden[(size_t)bg * 9 + k] = (double)cnt;
    }
    __syncthreads();

    int c = t;
    double acc[9] = {0, 0, 0, 0, 0, 0, 0, 0, 0};
    const float* xq = x + (size_t)c * HWP + (size_t)(by * 16 + g * 2) * IMW + bx * 16;
    #pragma unroll
    for (int r = 0; r < 2; ++r) {
        #pragma unroll
        for (int q = 0; q < 4; ++q) {
            float4 xw = *(const float4*)(xq + (size_t)r * IMW + q * 4);
            int pp = r * 16 + q * 4;
            #pragma unroll
            for (int k = 0; k < 9; ++k) {
                acc[k] = fma(aff[k][pp + 0], (double)xw.x, acc[k]);
                acc[k] = fma(aff[k][pp + 1], (double)xw.y, acc[k]);
                acc[k] = fma(aff[k][pp + 2], (double)xw.z, acc[k]);
                acc[k] = fma(aff[k][pp + 3], (double)xw.w, acc[k]);
            }
        }
    }
    #pragma unroll
    for (int k = 0; k < 9; ++k) bnum[((size_t)bg * 9 + k) * NC + c] = acc[k];
}

// ---- K5: paint means: 4-wave gather (wave j owns g = 2j, 2j+1) ------------
__global__ __launch_bounds__(256) void k_means_(const double* __restrict__ bnum,
                                                const double* __restrict__ bden,
                                                float* __restrict__ means) {
    int s = blockIdx.x, t = threadIdx.x, c = t & 63, j = t >> 6;
    int sy = s / NSW, sx = s % NSW;
    __shared__ double lnum[4][64];
    __shared__ double lden[4];
    double num = 0.0, den = 0.0;
    #pragma unroll
    for (int k = 0; k < 9; ++k) {
        int by2 = sy - (k / 3 - 1), bx2 = sx - (k % 3 - 1);
        if (by2 >= 0 && by2 < NSH && bx2 >= 0 && bx2 < NSW) {
            int b2 = by2 * NSW + bx2;
            #pragma unroll
            for (int gg = 0; gg < 2; ++gg) {
                int bg = b2 * 8 + j * 2 + gg;
                num += bnum[((size_t)bg * 9 + k) * NC + c];
                den += bden[(size_t)bg * 9 + k];
            }
        }
    }
    lnum[j][c] = num;
    if (c == 0) lden[j] = den;
    __syncthreads();
    if (t < 64) {
        double nt = ((lnum[0][c] + lnum[1][c]) + lnum[2][c]) + lnum[3][c];
        double dt = ((lden[0] + lden[1]) + lden[2]) + lden[3];
        means[s * NC + c] = (float)(nt / fmax(dt, 1.0));
    }
}

// ---- K6: paint out[c][p] = means[lab[p]][c]; 4 px x 4 ch per thread -------
__global__ __launch_bounds__(256) void k_paint(const int* __restrict__ labels,
                                               const float* __restrict__ means,
                                               float* __restrict__ out) {
    int p0 = (blockIdx.x * 256 + threadIdx.x) * 4;
    int4 lb = *(const int4*)&labels[p0];
    int c0 = blockIdx.y * 4;
    #pragma unroll
    for (int j = 0; j < 4; ++j) {
        int c = c0 + j;
        float4 o;
        o.x = means[lb.x * NC + c];
        o.y = means[lb.y * NC + c];
        o.z = means[lb.z * NC + c];
        o.w = means[lb.w * NC + c];
        *(float4*)&out[(size_t)c * HWP + p0] = o;
    }
}

extern "C" void kernel_launch(void* const* d_in, const int* in_sizes, int n_in,
                              void* d_out, int out_size, void* d_ws, size_t ws_size,
                              hipStream_t stream) {
    const float* x = (const float*)d_in[0];
    float* out = (float*)d_out;
    char* ws = (char*)d_ws;
    char* od = (char*)d_out;

    constexpr size_t CENT_B  = (size_t)NS * NC * 8;       // 294912 (x2)
    constexpr size_t CNRM_B  = (size_t)NS * 8;            // 4608   (x2)
    constexpr size_t BNUM_B  = (size_t)NBG * 9 * NC * 8;  // 21233664
    constexpr size_t BDEN_B  = (size_t)NBG * 9 * 8;       // 331776
    constexpr size_t LAB_B   = (size_t)HWP * 4;           // 589824
    constexpr size_t MEANS_B = (size_t)NS * NC * 4;       // 147456
    constexpr size_t T_PAINT = LAB_B + MEANS_B;           // must live in ws
    constexpr size_t T_CENT  = T_PAINT + 2 * (CENT_B + CNRM_B);
    constexpr size_t T_ALL   = T_CENT + BNUM_B + BDEN_B;  // ~22.9 MB

    int* labels = (int*)ws;
    float* means = (float*)(ws + LAB_B);
    double *centA, *centB, *cnormA, *cnormB, *bnum, *bden;
    if (ws_size >= T_ALL) {
        centA  = (double*)(ws + T_PAINT);
        centB  = (double*)(ws + T_PAINT + CENT_B);
        cnormA = (double*)(ws + T_PAINT + 2 * CENT_B);
        cnormB = (double*)(ws + T_PAINT + 2 * CENT_B + CNRM_B);
        bnum   = (double*)(ws + T_CENT);
        bden   = (double*)(ws + T_CENT + BNUM_B);
    } else if (ws_size >= T_CENT) {
        centA  = (double*)(ws + T_PAINT);
        centB  = (double*)(ws + T_PAINT + CENT_B);
        cnormA = (double*)(ws + T_PAINT + 2 * CENT_B);
        cnormB = (double*)(ws + T_PAINT + 2 * CENT_B + CNRM_B);
        bnum   = (double*)od;
        bden   = (double*)(od + BNUM_B);
    } else {
        bnum   = (double*)od;
        bden   = (double*)(od + BNUM_B);
        centA  = (double*)(od + BNUM_B + BDEN_B);
        centB  = (double*)(od + BNUM_B + BDEN_B + CENT_B);
        cnormA = (double*)(od + BNUM_B + BDEN_B + 2 * CENT_B);
        cnormB = (double*)(od + BNUM_B + BDEN_B + 2 * CENT_B + CNRM_B);
    }
    // all d_out-resident scratch (<22.3 MB) is consumed before k_paint
    // fully overwrites d_out (37.7 MB)

    k_cent_init<<<NS, 256, 0, stream>>>(x, centA, cnormA);
    k_iter<<<NBG, 64, 0, stream>>>(x, centA, cnormA, bnum, bden);
    k_gather_cent<<<NS, 256, 0, stream>>>(bnum, bden, centB, cnormB);
    k_iter<<<NBG, 64, 0, stream>>>(x, centB, cnormB, bnum, bden);
    k_gather_cent<<<NS, 256, 0, stream>>>(bnum, bden, centA, cnormA);
    k_final<<<NBG, 64, 0, stream>>>(x, centA, cnormA, labels, bnum, bden);
    k_means_<<<NS, 256, 0, stream>>>(bnum, bden, means);
    k_paint<<<dim3(HWP / 1024, NC / 4), 256, 0, stream>>>(labels, means, out);
}